// Round 4
// baseline (11905.612 us; speedup 1.0000x reference)
//
#include <hip/hip_runtime.h>

// GRU layer, B=64 T=512 D=512 H=1024, TF GRUCell semantics.
// v4: fence-free cross-WG comm via relaxed agent-scope atomics (sc1, straight
// to coherence point -- no buffer_wbl2 / buffer_inv L2 nukes), MFMA A-frags
// loaded direct from IF$ into registers (no LDS round-trip, no barrier on the
// critical path), x-projection staged off-path, lane-parallel flag polling.

#define NTHR 256
#define NISL 2
#define GWG  64               // gate WGs per island (32 cols each of 2048)
#define CWG  32               // cand WGs per island (32 cols each of 1024)
#define IWG  (GWG + CWG)      // 96
#define NWG  (NISL * IWG)     // 192
#define ROWS 32               // batch rows per island
#define TT   512
#define DD   512
#define HH   1024
#define KG   1536
#define WPG  1544             // gate weight LDS row stride (bf16 elems)
#define WPC  1032             // cand weight LDS row stride
#define XAP  520              // x LDS row stride
#define LDS_BYTES ((32 * WPG + 32 * XAP) * 2)   // (49408+16640)*2 = 132096 B
#define XP_LDS (2 * 64 * 264 * 2)               // xproj kernel LDS

// ws layout (bytes): flags @0 (island isl: flA = +isl*512, flB = flA+256)
#define WS_HB   4096
#define WS_RHB  (WS_HB + 64 * HH * 2)      // 135168
#define WS_UF   (WS_RHB + 64 * HH * 2)     // 266240
#define WS_NEED (WS_UF + 64 * HH * 4)      // 528384 (r2 proved ws >= this)

typedef __attribute__((ext_vector_type(8))) short          s16x8;
typedef __attribute__((ext_vector_type(4))) float          f32x4;
typedef __attribute__((ext_vector_type(4))) unsigned short us4;
typedef unsigned long long ull;
typedef unsigned short     ushort_t;

__device__ __forceinline__ unsigned short f2b(float f) {   // f32 -> bf16 RNE
  unsigned u = __float_as_uint(f);
  u += 0x7FFFu + ((u >> 16) & 1u);
  return (unsigned short)(u >> 16);
}
__device__ __forceinline__ float b2f(unsigned short b) {
  return __uint_as_float(((unsigned)b) << 16);
}

// ---- coherence-point (sc1) primitives ------------------------------------
__device__ __forceinline__ ull cload8(const void* p) {      // 8B device-coherent
  return __hip_atomic_load((const ull*)p, __ATOMIC_RELAXED, __HIP_MEMORY_SCOPE_AGENT);
}
__device__ __forceinline__ unsigned short cload2(const void* p) {
  return __hip_atomic_load((const unsigned short*)p, __ATOMIC_RELAXED,
                           __HIP_MEMORY_SCOPE_AGENT);
}
__device__ __forceinline__ float cloadf(const void* p) {
  return __hip_atomic_load((const float*)p, __ATOMIC_RELAXED, __HIP_MEMORY_SCOPE_AGENT);
}
__device__ __forceinline__ void cstore2(void* p, unsigned short v) {
  __hip_atomic_store((unsigned short*)p, v, __ATOMIC_RELAXED, __HIP_MEMORY_SCOPE_AGENT);
}
__device__ __forceinline__ void cstoref(void* p, float v) {
  __hip_atomic_store((float*)p, v, __ATOMIC_RELAXED, __HIP_MEMORY_SCOPE_AGENT);
}
// per-lane flag poll; exits loop when satisfied or capped
__device__ __forceinline__ bool poll_ge(const unsigned* p, unsigned e) {
  int polls = 0;
  while (__hip_atomic_load(p, __ATOMIC_RELAXED, __HIP_MEMORY_SCOPE_AGENT) < e) {
    __builtin_amdgcn_s_sleep(1);
    if (++polls > (1 << 16)) return false;
  }
  return true;
}

union FR { ull u[2]; s16x8 v; };

// stage x(t) [32 rows x 512] f32->bf16 into LDS (off critical path)
__device__ __forceinline__ void stage_x(unsigned short* Xs, const float* X,
                                        int isl, int t, int tid) {
  #pragma unroll
  for (int it = 0; it < 8; ++it) {
    int e = it * NTHR + tid;            // 2048 groups of 8 elems
    int row = e >> 6, c8 = e & 63;
    const float* src = X + ((size_t)(isl * ROWS + row) * TT + t) * DD + c8 * 8;
    float4 v0 = *(const float4*)src;
    float4 v1 = *(const float4*)(src + 4);
    us4 p0 = { f2b(v0.x), f2b(v0.y), f2b(v0.z), f2b(v0.w) };
    us4 p1 = { f2b(v1.x), f2b(v1.y), f2b(v1.z), f2b(v1.w) };
    unsigned short* dst = Xs + row * XAP + c8 * 8;
    *(us4*)dst = p0;
    *(us4*)(dst + 4) = p1;
  }
}

extern "C" __global__ void __launch_bounds__(NTHR, 1)
gru_persistent(const float* __restrict__ X, const float* __restrict__ GK,
               const float* __restrict__ GB, const float* __restrict__ CK,
               const float* __restrict__ CB, float* __restrict__ Y,
               unsigned char* __restrict__ ws) {
  extern __shared__ unsigned short lds[];
  unsigned short* Wt = lds;                 // gate [32][WPG] / cand [32][WPC]
  unsigned short* Xs = lds + 32 * WPG;      // gate only: [32][XAP]

  unsigned*       wsu = (unsigned*)ws;
  unsigned short* hb  = (unsigned short*)(ws + WS_HB);
  unsigned short* rhb = (unsigned short*)(ws + WS_RHB);
  float*          uf  = (float*)(ws + WS_UF);

  const int tid  = threadIdx.x;
  const int bid  = blockIdx.x;
  const int isl  = bid / IWG;
  const int iw   = bid % IWG;
  const int lane = tid & 63;
  const int w    = tid >> 6;
  const int rh2  = w & 1, ch2 = w >> 1;     // wave -> (row-tile, col-tile)
  const int r16  = lane & 15, g4 = lane >> 4;

  unsigned* flA = wsu + isl * 128;          // 64 gate flags
  unsigned* flB = flA + 64;                 // 32 cand flags

  bool bad = false;

  if (iw < GWG) {
    // ========================= GATE WG: 32 gate cols =========================
    const int cbase = iw * 32;
    {
      const int c = tid & 31;
      for (int k = tid >> 5; k < KG; k += 8)
        Wt[c * WPG + k] = f2b(GK[(size_t)k * (2 * HH) + cbase + c]);
    }
    const int   col  = cbase + ch2 * 16 + r16;
    const float bias = GB[col];
    const bool  isR  = (iw < 32);
    stage_x(Xs, X, isl, 0, tid);
    __syncthreads();

    const unsigned short* hrow =
        hb + (size_t)(isl * ROWS + rh2 * 16 + r16) * HH + g4 * 8;
    const unsigned short* wr = Wt + (ch2 * 16 + r16) * WPG + g4 * 8;
    const unsigned short* xr = Xs + (rh2 * 16 + r16) * XAP + g4 * 8;

    for (int t = 0; t < TT; ++t) {
      // ---- x-part MFMAs (independent of h -> before the wait) ----
      f32x4 acc0 = {0.f,0.f,0.f,0.f}, acc1 = {0.f,0.f,0.f,0.f};
      #pragma unroll
      for (int kk = 0; kk < 16; kk += 2) {
        acc0 = __builtin_amdgcn_mfma_f32_16x16x32_bf16(
                 *(const s16x8*)(xr + kk * 32), *(const s16x8*)(wr + kk * 32), acc0, 0,0,0);
        acc1 = __builtin_amdgcn_mfma_f32_16x16x32_bf16(
                 *(const s16x8*)(xr + kk * 32 + 32), *(const s16x8*)(wr + kk * 32 + 32), acc1, 0,0,0);
      }
      // ---- wait h(t-1) ----
      bool ok = poll_ge(&flB[lane & 31], (unsigned)t);
      if (!__all(ok)) { bad = true; break; }
      // epilogue h values for r-gates (issue early, consumed at the end)
      float hv[4];
      if (isR) {
        #pragma unroll
        for (int i = 0; i < 4; ++i) {
          int b = isl * ROWS + rh2 * 16 + g4 * 4 + i;
          hv[i] = b2f(cload2(hb + (size_t)b * HH + col));
        }
      }
      // ---- h-part: direct coherence-point A-frags, rolling double buffer ----
      FR cur[8], nxt[8];
      #pragma unroll
      for (int f = 0; f < 8; ++f) {
        cur[f].u[0] = cload8(hrow + f * 32);
        cur[f].u[1] = cload8(hrow + f * 32 + 4);
      }
      #pragma unroll
      for (int c = 0; c < 4; ++c) {
        if (c < 3) {
          #pragma unroll
          for (int f = 0; f < 8; ++f) {
            nxt[f].u[0] = cload8(hrow + (c + 1) * 256 + f * 32);
            nxt[f].u[1] = cload8(hrow + (c + 1) * 256 + f * 32 + 4);
          }
        }
        const unsigned short* wh = wr + 512 + c * 256;
        #pragma unroll
        for (int f = 0; f < 8; f += 2) {
          acc0 = __builtin_amdgcn_mfma_f32_16x16x32_bf16(
                   cur[f].v, *(const s16x8*)(wh + f * 32), acc0, 0,0,0);
          acc1 = __builtin_amdgcn_mfma_f32_16x16x32_bf16(
                   cur[f+1].v, *(const s16x8*)(wh + f * 32 + 32), acc1, 0,0,0);
        }
        if (c < 3) {
          #pragma unroll
          for (int f = 0; f < 8; ++f) cur[f] = nxt[f];
        }
      }
      // ---- epilogue: sigmoid, publish r*h or u ----
      #pragma unroll
      for (int i = 0; i < 4; ++i) {
        int b = isl * ROWS + rh2 * 16 + g4 * 4 + i;
        float val = acc0[i] + acc1[i] + bias;
        float g = 1.f / (1.f + __expf(-val));
        if (isR) cstore2(rhb + (size_t)b * HH + col, f2b(g * hv[i]));
        else     cstoref(uf + (size_t)b * HH + col - HH, g);
      }
      __syncthreads();                          // drain sc1 stores (vmcnt 0)
      if (tid == 0)
        __hip_atomic_store(&flA[iw], (unsigned)(t + 1), __ATOMIC_RELAXED,
                           __HIP_MEMORY_SCOPE_AGENT);
      if (t + 1 < TT) stage_x(Xs, X, isl, t + 1, tid);   // hidden under cand phase
      __syncthreads();
    }
  } else {
    // ========================= CAND WG: 32 cand cols =========================
    const int ic    = iw - GWG;
    const int cbase = ic * 32;
    {
      const int c = tid & 31;
      for (int k = tid >> 5; k < HH; k += 8)
        Wt[c * WPC + k] = f2b(CK[(size_t)(DD + k) * HH + cbase + c]);
    }
    const int   col  = cbase + ch2 * 16 + r16;
    const float bias = CB[col];
    float hreg[4] = {0.f, 0.f, 0.f, 0.f};
    __syncthreads();

    const unsigned short* rrow =
        rhb + (size_t)(isl * ROWS + rh2 * 16 + r16) * HH + g4 * 8;
    const unsigned short* wr = Wt + (ch2 * 16 + r16) * WPC + g4 * 8;

    for (int t = 0; t < TT; ++t) {
      float xp[4];                              // Xp in Y slot t (normal loads)
      #pragma unroll
      for (int i = 0; i < 4; ++i) {
        int b = isl * ROWS + rh2 * 16 + g4 * 4 + i;
        xp[i] = Y[((size_t)b * TT + t) * HH + col];
      }
      bool ok = poll_ge(&flA[lane], (unsigned)(t + 1));
      if (!__all(ok)) { bad = true; break; }
      float uv[4];                              // u (issue early)
      #pragma unroll
      for (int i = 0; i < 4; ++i) {
        int b = isl * ROWS + rh2 * 16 + g4 * 4 + i;
        uv[i] = cloadf(uf + (size_t)b * HH + col);
      }
      // ---- cand GEMM: K=1024 over r*h, direct coherence-point A-frags ----
      f32x4 acc0 = {0.f,0.f,0.f,0.f}, acc1 = {0.f,0.f,0.f,0.f};
      FR cur[8], nxt[8];
      #pragma unroll
      for (int f = 0; f < 8; ++f) {
        cur[f].u[0] = cload8(rrow + f * 32);
        cur[f].u[1] = cload8(rrow + f * 32 + 4);
      }
      #pragma unroll
      for (int c = 0; c < 4; ++c) {
        if (c < 3) {
          #pragma unroll
          for (int f = 0; f < 8; ++f) {
            nxt[f].u[0] = cload8(rrow + (c + 1) * 256 + f * 32);
            nxt[f].u[1] = cload8(rrow + (c + 1) * 256 + f * 32 + 4);
          }
        }
        const unsigned short* wh = wr + c * 256;
        #pragma unroll
        for (int f = 0; f < 8; f += 2) {
          acc0 = __builtin_amdgcn_mfma_f32_16x16x32_bf16(
                   cur[f].v, *(const s16x8*)(wh + f * 32), acc0, 0,0,0);
          acc1 = __builtin_amdgcn_mfma_f32_16x16x32_bf16(
                   cur[f+1].v, *(const s16x8*)(wh + f * 32 + 32), acc1, 0,0,0);
        }
        if (c < 3) {
          #pragma unroll
          for (int f = 0; f < 8; ++f) cur[f] = nxt[f];
        }
      }
      // ---- epilogue: tanh, h update, publish ----
      #pragma unroll
      for (int i = 0; i < 4; ++i) {
        int b = isl * ROWS + rh2 * 16 + g4 * 4 + i;
        float cv = tanhf(acc0[i] + acc1[i] + xp[i] + bias);
        float hn = uv[i] * hreg[i] + (1.f - uv[i]) * cv;
        hreg[i] = hn;
        Y[((size_t)b * TT + t) * HH + col] = hn;        // overwrites consumed Xp
        cstore2(hb + (size_t)b * HH + col, f2b(hn));
      }
      __syncthreads();                          // drain sc1 stores
      if (tid == 0)
        __hip_atomic_store(&flB[ic], (unsigned)(t + 1), __ATOMIC_RELAXED,
                           __HIP_MEMORY_SCOPE_AGENT);
    }
  }
  if (bad && tid == 0) Y[1] = 31337.f;          // visible failure sentinel
}

// ---- one-time x-projection GEMM: Y <- X[32768,512] @ CK[0:512, :] ----------
extern "C" __global__ void __launch_bounds__(NTHR, 1)
xproj_gemm(const float* __restrict__ X, const float* __restrict__ CK,
           float* __restrict__ Y) {
  extern __shared__ unsigned short lds[];
  unsigned short* Ax = lds;             // [64][264]
  unsigned short* Bx = lds + 64 * 264;  // [64][264]
  const int tid = threadIdx.x;
  const int lane = tid & 63, w = tid >> 6;
  const int r16 = lane & 15, g4 = lane >> 4;
  const int nt = blockIdx.x & 15, mt = blockIdx.x >> 4;
  const size_t m0 = (size_t)mt * 64;
  const int n0 = nt * 64;

  f32x4 acc[4][2];
  #pragma unroll
  for (int ct = 0; ct < 4; ++ct) {
    acc[ct][0] = (f32x4){0.f,0.f,0.f,0.f};
    acc[ct][1] = (f32x4){0.f,0.f,0.f,0.f};
  }
  for (int ch = 0; ch < 2; ++ch) {
    const int k0 = ch * 256;
    #pragma unroll
    for (int it = 0; it < 8; ++it) {
      int e = it * NTHR + tid;
      int row = e >> 5, c8 = e & 31;
      const float* src = X + (m0 + row) * 512 + k0 + c8 * 8;
      float4 v0 = *(const float4*)src;
      float4 v1 = *(const float4*)(src + 4);
      us4 p0 = { f2b(v0.x), f2b(v0.y), f2b(v0.z), f2b(v0.w) };
      us4 p1 = { f2b(v1.x), f2b(v1.y), f2b(v1.z), f2b(v1.w) };
      unsigned short* dst = Ax + row * 264 + c8 * 8;
      *(us4*)dst = p0;
      *(us4*)(dst + 4) = p1;
    }
    #pragma unroll
    for (int it = 0; it < 16; ++it) {
      int q = it * NTHR + tid;
      int k = q >> 4, cq = q & 15;
      float4 v = *(const float4*)(CK + (size_t)(k0 + k) * HH + n0 + cq * 4);
      Bx[(cq * 4 + 0) * 264 + k] = f2b(v.x);
      Bx[(cq * 4 + 1) * 264 + k] = f2b(v.y);
      Bx[(cq * 4 + 2) * 264 + k] = f2b(v.z);
      Bx[(cq * 4 + 3) * 264 + k] = f2b(v.w);
    }
    __syncthreads();
    #pragma unroll
    for (int ct = 0; ct < 4; ++ct) {
      const unsigned short* ar = Ax + (w * 16 + r16) * 264 + g4 * 8;
      const unsigned short* br = Bx + (ct * 16 + r16) * 264 + g4 * 8;
      #pragma unroll
      for (int kk = 0; kk < 8; ++kk) {
        s16x8 av = *(const s16x8*)(ar + kk * 32);
        s16x8 bv = *(const s16x8*)(br + kk * 32);
        acc[ct][kk & 1] =
            __builtin_amdgcn_mfma_f32_16x16x32_bf16(av, bv, acc[ct][kk & 1], 0, 0, 0);
      }
    }
    __syncthreads();
  }
  #pragma unroll
  for (int ct = 0; ct < 4; ++ct) {
    #pragma unroll
    for (int i = 0; i < 4; ++i) {
      float v = acc[ct][0][i] + acc[ct][1][i];
      Y[(m0 + w * 16 + g4 * 4 + i) * HH + n0 + ct * 16 + r16] = v;
    }
  }
}

extern "C" __global__ void gru_sentinel(float* out, float v) {
  if (blockIdx.x == 0 && threadIdx.x == 0) out[0] = v;
}

extern "C" void kernel_launch(void* const* d_in, const int* in_sizes, int n_in,
                              void* d_out, int out_size, void* d_ws, size_t ws_size,
                              hipStream_t stream) {
  const float* X  = (const float*)d_in[0];
  const float* GK = (const float*)d_in[1];
  const float* GB = (const float*)d_in[2];
  const float* CK = (const float*)d_in[3];
  const float* CB = (const float*)d_in[4];
  float* Y = (float*)d_out;
  unsigned char* wsb = (unsigned char*)d_ws;

  if (ws_size < (size_t)WS_NEED) {
    gru_sentinel<<<1, 64, 0, stream>>>(Y, 1000.f + (float)(ws_size >> 20));
    return;
  }

  // zero flags + h mirror (h0 = 0); deterministic each call
  hipMemsetAsync(d_ws, 0, WS_HB + 64 * HH * 2, stream);

  (void)hipFuncSetAttribute((const void*)xproj_gemm,
                            hipFuncAttributeMaxDynamicSharedMemorySize, XP_LDS);
  xproj_gemm<<<dim3(512 * 16), dim3(NTHR), XP_LDS, stream>>>(X, CK, Y);

  (void)hipFuncSetAttribute((const void*)gru_persistent,
                            hipFuncAttributeMaxDynamicSharedMemorySize, LDS_BYTES);
  gru_persistent<<<dim3(NWG), dim3(NTHR), LDS_BYTES, stream>>>(X, GK, GB, CK, CB, Y, wsb);
}

// Round 5
// 7253.382 us; speedup vs baseline: 1.6414x; 1.6414x over previous
//
#include <hip/hip_runtime.h>

// GRU layer, B=64 T=512 D=512 H=1024, TF GRUCell semantics.
// v5: 4 islands x 16 rows (XCD-pair pinned), 32 R-WGs + 32 C-WGs per island.
// u-gate computed locally by C-WGs (off exchange); xp_c/xp_u packed bf16x2 in Y.
// Exchange via relaxed agent-scope (sc1) ops only; wide u16-flag polls;
// LDS-staged A operands (T14 split) with T2 XOR swizzle; hb double-buffered.

#define NTHR 256
#define NISL 4
#define RPI  16               // rows per island
#define TT   512
#define DD   512
#define HH   1024

// LDS element offsets (ushort units)
#define R_XS_OFF   49152      // R: Wg[32][1536] @0, Xs[16][512], Ash[16][512]
#define R_ASH_OFF  57344
#define C_WC_OFF   32768      // C: Wu[32][1024] @0, Wc[32][1024], Ash[16][512]
#define C_ASH_OFF  65536
#define LDS_BYTES  147456     // C variant: 73728 elems * 2B
#define XP_LDS     (3 * 64 * 264 * 2)   // xproj_dual: 101376 B

// ws layout (bytes)
#define WS_FL    0            // island isl: flA @ isl*256 (32 u16), flB @ +128
#define WS_HB    4096         // hb[2][64][1024] bf16 (262144 B), parity-buffered
#define WS_RHB   266240       // rhb[64][1024] bf16 (131072 B)
#define WS_NEED  397312

typedef __attribute__((ext_vector_type(8))) short          s16x8;
typedef __attribute__((ext_vector_type(4))) float          f32x4;
typedef __attribute__((ext_vector_type(4))) unsigned short us4;
typedef unsigned long long ull;

__device__ __forceinline__ unsigned short f2b(float f) {   // f32 -> bf16 RNE
  unsigned u = __float_as_uint(f);
  u += 0x7FFFu + ((u >> 16) & 1u);
  return (unsigned short)(u >> 16);
}
__device__ __forceinline__ float b2f(unsigned short b) {
  return __uint_as_float(((unsigned)b) << 16);
}

// ---- device-coherent (sc1) primitives -------------------------------------
__device__ __forceinline__ ull cload8(const void* p) {
  return __hip_atomic_load((const ull*)p, __ATOMIC_RELAXED, __HIP_MEMORY_SCOPE_AGENT);
}
__device__ __forceinline__ unsigned short cload2(const void* p) {
  return __hip_atomic_load((const unsigned short*)p, __ATOMIC_RELAXED,
                           __HIP_MEMORY_SCOPE_AGENT);
}
__device__ __forceinline__ void cstore2(void* p, unsigned short v) {
  __hip_atomic_store((unsigned short*)p, v, __ATOMIC_RELAXED, __HIP_MEMORY_SCOPE_AGENT);
}

// wide poll: 32 u16 epoch flags checked by lanes 0..7 (8B each); uniform exit
__device__ __forceinline__ bool wait_fl(const unsigned short* fl, unsigned e, int lane) {
  int polls = 0;
  for (;;) {
    bool ok = true;
    if (lane < 8) {
      ull v = cload8(fl + lane * 4);
      ok = ((unsigned)(v & 0xFFFF) >= e) & ((unsigned)((v >> 16) & 0xFFFF) >= e) &
           ((unsigned)((v >> 32) & 0xFFFF) >= e) & ((unsigned)(v >> 48) >= e);
    }
    if (__all(ok)) return true;
    if (++polls > (1 << 17)) return false;
    __builtin_amdgcn_s_sleep(2);
  }
}

// ---- A-operand staging: global(sc1) -> regs -> LDS (swizzled) -------------
struct StReg { ull v[8]; };
__device__ __forceinline__ void stage_load(StReg& s, const unsigned short* src, int kb, int tid) {
  const int row = tid >> 4, lp = tid & 15, eb = lp * 32;
  const unsigned short* p = src + (size_t)row * HH + kb + eb;
  #pragma unroll
  for (int j = 0; j < 8; ++j) s.v[j] = cload8(p + j * 4);
}
__device__ __forceinline__ void stage_write(const StReg& s, unsigned short* Ash, int tid) {
  const int row = tid >> 4, lp = tid & 15, eb = lp * 32, m = (row & 7) << 3;
  #pragma unroll
  for (int j = 0; j < 8; ++j)
    *(ull*)(Ash + row * 512 + ((eb + j * 4) ^ m)) = s.v[j];
}

// stage x(t) [16 rows x 512] f32->bf16 into Xs (swizzled), off critical path
__device__ __forceinline__ void stage_xs(unsigned short* Xs, const float* X,
                                         int islbase, int t, int tid) {
  const int row = tid >> 4, lp = tid & 15, eb = lp * 32, m = (row & 7) << 3;
  const float* src = X + ((size_t)(islbase + row) * TT + t) * DD + eb;
  #pragma unroll
  for (int j = 0; j < 8; ++j) {
    float4 v = *(const float4*)(src + j * 4);
    us4 p = { f2b(v.x), f2b(v.y), f2b(v.z), f2b(v.w) };
    *(us4*)(Xs + row * 512 + ((eb + j * 4) ^ m)) = p;
  }
}

// one 16x16 tile over a K=512 half; A/B LDS reads XOR-swizzled (T2)
__device__ __forceinline__ void mm_half(const unsigned short* A, const unsigned short* W,
                                        const int wstride, const int kbase, const int c,
                                        const int r16, const int g4, f32x4& a0, f32x4& a1) {
  const int am = (r16 & 7) << 3, bm = (c & 7) << 3;
  const unsigned short* arow = A + r16 * 512;
  const unsigned short* brow = W + c * wstride + kbase;
  #pragma unroll
  for (int f = 0; f < 16; f += 2) {
    const int k0 = f * 32 + g4 * 8, k1 = k0 + 32;
    s16x8 av0 = *(const s16x8*)(arow + (k0 ^ am));
    s16x8 bv0 = *(const s16x8*)(brow + (k0 ^ bm));
    s16x8 av1 = *(const s16x8*)(arow + (k1 ^ am));
    s16x8 bv1 = *(const s16x8*)(brow + (k1 ^ bm));
    a0 = __builtin_amdgcn_mfma_f32_16x16x32_bf16(av0, bv0, a0, 0, 0, 0);
    a1 = __builtin_amdgcn_mfma_f32_16x16x32_bf16(av1, bv1, a1, 0, 0, 0);
  }
}

extern "C" __global__ void __launch_bounds__(NTHR, 1)
gru_persistent(const float* __restrict__ X, const float* __restrict__ GK,
               const float* __restrict__ GB, const float* __restrict__ CK,
               const float* __restrict__ CB, float* __restrict__ Y,
               unsigned char* __restrict__ ws) {
  extern __shared__ unsigned short lds[];
  const int tid = threadIdx.x, bid = blockIdx.x;
  const int isl = (bid & 7) >> 1;                  // XCD pair {2i,2i+1}
  const int iw  = ((bid >> 3) << 1) | (bid & 1);   // 0..63 within island
  const int islbase = isl * RPI;
  const int lane = tid & 63, w = tid >> 6;
  const int r16 = lane & 15, g4 = lane >> 4;
  const int ct = w & 1;                            // col-tile (waves 2,3 duplicate)

  unsigned short* flA = (unsigned short*)(ws + (size_t)isl * 256);        // r done
  unsigned short* flB = (unsigned short*)(ws + (size_t)isl * 256 + 128);  // h done
  unsigned short* hb  = (unsigned short*)(ws + WS_HB);
  unsigned short* rhb = (unsigned short*)(ws + WS_RHB);

  bool bad = false;

  if (iw < 32) {
    // ================= R-WG: 32 reset-gate cols, publish r*h =================
    unsigned short* Wg  = lds;                     // [32][1536] swizzled
    unsigned short* Xs  = lds + R_XS_OFF;          // [16][512]
    unsigned short* Ash = lds + R_ASH_OFF;         // [16][512]
    const int cbase = iw * 32;
    {
      const int c = tid & 31;
      for (int k = tid >> 5; k < 1536; k += 8)
        Wg[c * 1536 + (k ^ ((c & 7) << 3))] = f2b(GK[(size_t)k * 2048 + cbase + c]);
    }
    const int   cc   = ct * 16 + r16;
    const int   col  = cbase + cc;
    const float bias = GB[col];
    stage_xs(Xs, X, islbase, 0, tid);
    __syncthreads();

    for (int t = 0; t < TT; ++t) {
      f32x4 a0 = {0.f,0.f,0.f,0.f}, a1 = {0.f,0.f,0.f,0.f};
      mm_half(Xs, Wg, 1536, 0, cc, r16, g4, a0, a1);     // x-part, pre-poll
      if (!wait_fl(flB, (unsigned)t, lane)) { bad = true; break; }
      const unsigned short* hbR = hb + ((t + 1) & 1) * 65536 + (size_t)islbase * HH;
      float hv[4];                                       // own-col h(t-1)
      #pragma unroll
      for (int i = 0; i < 4; ++i)
        hv[i] = b2f(cload2(hbR + (size_t)(g4 * 4 + i) * HH + col));
      StReg s0, s1;
      stage_load(s0, hbR, 0, tid);
      stage_write(s0, Ash, tid);
      stage_load(s1, hbR, 512, tid);
      __syncthreads();
      mm_half(Ash, Wg, 1536, 512, cc, r16, g4, a0, a1);
      __syncthreads();
      stage_write(s1, Ash, tid);
      __syncthreads();
      mm_half(Ash, Wg, 1536, 1024, cc, r16, g4, a0, a1);
      #pragma unroll
      for (int i = 0; i < 4; ++i) {                      // C/D: row=g4*4+i, col=r16
        float rv = 1.f / (1.f + __expf(-(a0[i] + a1[i] + bias)));
        if (w < 2)
          cstore2(rhb + (size_t)(islbase + g4 * 4 + i) * HH + col, f2b(rv * hv[i]));
      }
      __syncthreads();                                   // drain rhb stores
      if (tid == 0) cstore2(flA + iw, (unsigned short)(t + 1));
      if (t + 1 < TT) stage_xs(Xs, X, islbase, t + 1, tid);  // hidden under C phase
      __syncthreads();
    }
  } else {
    // ====== C-WG: 32 cols; u computed locally (off exchange) + cand + h ======
    unsigned short* Wu  = lds;                     // [32][1024] swizzled
    unsigned short* Wc  = lds + C_WC_OFF;          // [32][1024]
    unsigned short* Ash = lds + C_ASH_OFF;         // [16][512]
    const int ic = iw - 32, cbase = ic * 32;
    {
      const int c = tid & 31;
      for (int k = tid >> 5; k < 1024; k += 8) {
        const int sw = (k ^ ((c & 7) << 3));
        Wu[c * 1024 + sw] = f2b(GK[(size_t)(512 + k) * 2048 + 1024 + cbase + c]);
        Wc[c * 1024 + sw] = f2b(CK[(size_t)(512 + k) * 1024 + cbase + c]);
      }
    }
    const int   cc    = ct * 16 + r16;
    const int   col   = cbase + cc;
    const float ubias = GB[1024 + col];
    const float cbias = CB[col];
    float hreg[4] = {0.f, 0.f, 0.f, 0.f};
    const unsigned* Yw = (const unsigned*)Y;
    __syncthreads();

    for (int t = 0; t < TT; ++t) {
      unsigned xw[4];                              // packed (xp_u<<16 | xp_c)
      #pragma unroll
      for (int i = 0; i < 4; ++i)
        xw[i] = Yw[((size_t)(islbase + g4 * 4 + i) * TT + t) * HH + col];
      if (!wait_fl(flB, (unsigned)t, lane)) { bad = true; break; }
      const unsigned short* hbR = hb + ((t + 1) & 1) * 65536 + (size_t)islbase * HH;
      unsigned short*       hbW = hb + (t & 1) * 65536;
      // ---- u-GEMM over h(t-1): runs concurrent with R phase ----
      f32x4 u0 = {0.f,0.f,0.f,0.f}, u1 = {0.f,0.f,0.f,0.f};
      StReg s0, s1;
      stage_load(s0, hbR, 0, tid);
      stage_write(s0, Ash, tid);
      stage_load(s1, hbR, 512, tid);
      __syncthreads();
      mm_half(Ash, Wu, 1024, 0, cc, r16, g4, u0, u1);
      __syncthreads();
      stage_write(s1, Ash, tid);
      __syncthreads();
      mm_half(Ash, Wu, 1024, 512, cc, r16, g4, u0, u1);
      float uv[4];
      #pragma unroll
      for (int i = 0; i < 4; ++i)
        uv[i] = 1.f / (1.f + __expf(-(u0[i] + u1[i] +
                    b2f((unsigned short)(xw[i] >> 16)) + ubias)));
      // ---- cand GEMM over r*h(t) ----
      if (!wait_fl(flA, (unsigned)(t + 1), lane)) { bad = true; break; }
      const unsigned short* rhI = rhb + (size_t)islbase * HH;
      f32x4 c0 = {0.f,0.f,0.f,0.f}, c1 = {0.f,0.f,0.f,0.f};
      stage_load(s0, rhI, 0, tid);
      __syncthreads();                             // u-half1 reads done before overwrite
      stage_write(s0, Ash, tid);
      stage_load(s1, rhI, 512, tid);
      __syncthreads();
      mm_half(Ash, Wc, 1024, 0, cc, r16, g4, c0, c1);
      __syncthreads();
      stage_write(s1, Ash, tid);
      __syncthreads();
      mm_half(Ash, Wc, 1024, 512, cc, r16, g4, c0, c1);
      #pragma unroll
      for (int i = 0; i < 4; ++i) {
        float cv = tanhf(c0[i] + c1[i] + b2f((unsigned short)(xw[i] & 0xFFFF)) + cbias);
        float hn = uv[i] * hreg[i] + (1.f - uv[i]) * cv;
        hreg[i] = hn;
        if (w < 2) {
          Y[((size_t)(islbase + g4 * 4 + i) * TT + t) * HH + col] = hn;
          cstore2(hbW + (size_t)(islbase + g4 * 4 + i) * HH + col, f2b(hn));
        }
      }
      __syncthreads();                             // drain h stores
      if (tid == 0) cstore2(flB + ic, (unsigned short)(t + 1));
    }
  }
  if (bad && tid == 0) Y[1] = 31337.f;             // visible failure sentinel
}

// ---- one-time dual x-projection: Yw <- pack(bf16(X@GKu), bf16(X@CKc)) ------
extern "C" __global__ void __launch_bounds__(NTHR, 1)
xproj_dual(const float* __restrict__ X, const float* __restrict__ CK,
           const float* __restrict__ GK, unsigned* __restrict__ Yw) {
  extern __shared__ unsigned short lds[];
  unsigned short* Ax = lds;                 // [64][264]
  unsigned short* Bc = lds + 64 * 264;
  unsigned short* Bu = lds + 2 * 64 * 264;
  const int tid = threadIdx.x, lane = tid & 63, w = tid >> 6;
  const int r16 = lane & 15, g4 = lane >> 4;
  const int nt = blockIdx.x & 15, mt = blockIdx.x >> 4;
  const size_t m0 = (size_t)mt * 64;
  const int n0 = nt * 64;

  f32x4 ac[4][2], au[4][2];
  #pragma unroll
  for (int i = 0; i < 4; ++i) {
    ac[i][0] = (f32x4){0.f,0.f,0.f,0.f}; ac[i][1] = (f32x4){0.f,0.f,0.f,0.f};
    au[i][0] = (f32x4){0.f,0.f,0.f,0.f}; au[i][1] = (f32x4){0.f,0.f,0.f,0.f};
  }
  for (int ch = 0; ch < 2; ++ch) {
    const int k0 = ch * 256;
    #pragma unroll
    for (int it = 0; it < 8; ++it) {               // A 64x256
      int e = it * NTHR + tid, row = e >> 5, c8 = e & 31;
      const float* src = X + (m0 + row) * 512 + k0 + c8 * 8;
      float4 v0 = *(const float4*)src;
      float4 v1 = *(const float4*)(src + 4);
      us4 p0 = { f2b(v0.x), f2b(v0.y), f2b(v0.z), f2b(v0.w) };
      us4 p1 = { f2b(v1.x), f2b(v1.y), f2b(v1.z), f2b(v1.w) };
      unsigned short* dst = Ax + row * 264 + c8 * 8;
      *(us4*)dst = p0; *(us4*)(dst + 4) = p1;
    }
    #pragma unroll
    for (int it = 0; it < 16; ++it) {              // B tiles (transposed)
      int q = it * NTHR + tid, k = q >> 4, cq = q & 15;
      float4 v = *(const float4*)(CK + (size_t)(k0 + k) * HH + n0 + cq * 4);
      float4 vu = *(const float4*)(GK + (size_t)(k0 + k) * 2048 + 1024 + n0 + cq * 4);
      Bc[(cq * 4 + 0) * 264 + k] = f2b(v.x);  Bc[(cq * 4 + 1) * 264 + k] = f2b(v.y);
      Bc[(cq * 4 + 2) * 264 + k] = f2b(v.z);  Bc[(cq * 4 + 3) * 264 + k] = f2b(v.w);
      Bu[(cq * 4 + 0) * 264 + k] = f2b(vu.x); Bu[(cq * 4 + 1) * 264 + k] = f2b(vu.y);
      Bu[(cq * 4 + 2) * 264 + k] = f2b(vu.z); Bu[(cq * 4 + 3) * 264 + k] = f2b(vu.w);
    }
    __syncthreads();
    #pragma unroll
    for (int ctt = 0; ctt < 4; ++ctt) {
      const unsigned short* ar = Ax + (w * 16 + r16) * 264 + g4 * 8;
      const unsigned short* bc = Bc + (ctt * 16 + r16) * 264 + g4 * 8;
      const unsigned short* bu = Bu + (ctt * 16 + r16) * 264 + g4 * 8;
      #pragma unroll
      for (int kk = 0; kk < 8; ++kk) {
        s16x8 av = *(const s16x8*)(ar + kk * 32);
        ac[ctt][kk & 1] = __builtin_amdgcn_mfma_f32_16x16x32_bf16(
            av, *(const s16x8*)(bc + kk * 32), ac[ctt][kk & 1], 0, 0, 0);
        au[ctt][kk & 1] = __builtin_amdgcn_mfma_f32_16x16x32_bf16(
            av, *(const s16x8*)(bu + kk * 32), au[ctt][kk & 1], 0, 0, 0);
      }
    }
    __syncthreads();
  }
  #pragma unroll
  for (int ctt = 0; ctt < 4; ++ctt) {
    #pragma unroll
    for (int i = 0; i < 4; ++i) {
      float xc = ac[ctt][0][i] + ac[ctt][1][i];
      float xu = au[ctt][0][i] + au[ctt][1][i];
      Yw[(m0 + w * 16 + g4 * 4 + i) * HH + n0 + ctt * 16 + r16] =
          ((unsigned)f2b(xu) << 16) | (unsigned)f2b(xc);
    }
  }
}

extern "C" __global__ void gru_sentinel(float* out, float v) {
  if (blockIdx.x == 0 && threadIdx.x == 0) out[0] = v;
}

extern "C" void kernel_launch(void* const* d_in, const int* in_sizes, int n_in,
                              void* d_out, int out_size, void* d_ws, size_t ws_size,
                              hipStream_t stream) {
  const float* X  = (const float*)d_in[0];
  const float* GK = (const float*)d_in[1];
  const float* GB = (const float*)d_in[2];
  const float* CK = (const float*)d_in[3];
  const float* CB = (const float*)d_in[4];
  float* Y = (float*)d_out;
  unsigned char* wsb = (unsigned char*)d_ws;

  if (ws_size < (size_t)WS_NEED) {
    gru_sentinel<<<1, 64, 0, stream>>>(Y, 1000.f + (float)(ws_size >> 20));
    return;
  }

  // zero flags + both h parity buffers (h0 = 0); deterministic each call
  hipMemsetAsync(d_ws, 0, WS_HB + 2 * 64 * HH * 2, stream);

  (void)hipFuncSetAttribute((const void*)xproj_dual,
                            hipFuncAttributeMaxDynamicSharedMemorySize, XP_LDS);
  xproj_dual<<<dim3(512 * 16), dim3(NTHR), XP_LDS, stream>>>(X, CK, GK, (unsigned*)Y);

  (void)hipFuncSetAttribute((const void*)gru_persistent,
                            hipFuncAttributeMaxDynamicSharedMemorySize, LDS_BYTES);
  gru_persistent<<<dim3(256), dim3(NTHR), LDS_BYTES, stream>>>(X, GK, GB, CK, CB, Y, wsb);
}

// Round 7
// 7128.752 us; speedup vs baseline: 1.6701x; 1.0175x over previous
//
#include <hip/hip_runtime.h>

// GRU layer, B=64 T=512 D=512 H=1024, TF GRUCell semantics.
// v7 = v6 with the xproj_dual u-weight row-index fix ((512+k) -> k).
// v6 notes: conflict-free LDS staging (padded strides), in-register quad
// transpose -> 8B sc1 publishes, x-staging overlapped with poll, fast xproj.

#define NTHR 256
#define RPI  16               // rows per island (4 islands)
#define TT   512
#define DD   512
#define HH   1024
#define AP   520              // staged-A half-K row stride (elems); 260w = 4 mod 32
#define WPG  1544             // gate weight stride; 772w = 4 mod 32
#define WPC  1028             // cand/u weight stride; 514w = 2 mod 32

// LDS elem offsets
#define R_XS   49408          // R: Wg[32][1544] @0, Xs[16][520], Ash[16][520]
#define R_ASH  57728
#define C_WC   32896          // C: Wu[32][1028] @0, Wc[32][1028], Ash[16][520]
#define C_ASH  65792
#define LDS_BYTES 148224      // max(R 132096, C 148224)
#define XP_LDSB   149760      // xproj: Bc[64][520], Bu[64][520], Axs[16][520]

// ws layout (bytes)
#define WS_HB    4096         // hb[2][64][1024] bf16, parity-buffered (262144 B)
#define WS_RHB   266240       // rhb[64][1024] bf16 (131072 B)
#define WS_NEED  397312

typedef __attribute__((ext_vector_type(8))) short          s16x8;
typedef __attribute__((ext_vector_type(4))) float          f32x4;
typedef __attribute__((ext_vector_type(4))) unsigned short us4;
typedef unsigned long long ull;
typedef unsigned short us;

__device__ __forceinline__ us f2b(float f) {               // f32 -> bf16 RNE
  unsigned u = __float_as_uint(f);
  u += 0x7FFFu + ((u >> 16) & 1u);
  return (us)(u >> 16);
}
__device__ __forceinline__ float b2f(us b) { return __uint_as_float(((unsigned)b) << 16); }

// ---- device-coherent (sc1) primitives -------------------------------------
__device__ __forceinline__ ull cload8(const void* p) {
  return __hip_atomic_load((const ull*)p, __ATOMIC_RELAXED, __HIP_MEMORY_SCOPE_AGENT);
}
__device__ __forceinline__ void cstore8(void* p, ull v) {
  __hip_atomic_store((ull*)p, v, __ATOMIC_RELAXED, __HIP_MEMORY_SCOPE_AGENT);
}
__device__ __forceinline__ void cstore2(void* p, us v) {
  __hip_atomic_store((us*)p, v, __ATOMIC_RELAXED, __HIP_MEMORY_SCOPE_AGENT);
}
// 32 u16 epoch flags polled by lanes 0..7 (8B each); uniform exit
__device__ __forceinline__ bool wait_fl(const us* fl, unsigned e, int lane) {
  int polls = 0;
  for (;;) {
    bool ok = true;
    if (lane < 8) {
      ull v = cload8(fl + lane * 4);
      ok = ((unsigned)(v & 0xFFFF) >= e) & ((unsigned)((v >> 16) & 0xFFFF) >= e) &
           ((unsigned)((v >> 32) & 0xFFFF) >= e) & ((unsigned)(v >> 48) >= e);
    }
    if (__all(ok)) return true;
    if (++polls > (1 << 17)) return false;
    __builtin_amdgcn_s_sleep(1);
  }
}

// ---- staging (half K=512): thread(row=tid>>4, lp=tid&15), chunks lp*4+j*64 --
struct StReg { ull v[8]; };
__device__ __forceinline__ void stage_load(StReg& s, const us* src, int kb, int row, int lp) {
  const us* p = src + (size_t)row * HH + kb + lp * 4;
  #pragma unroll
  for (int j = 0; j < 8; ++j) s.v[j] = cload8(p + j * 64);
}
__device__ __forceinline__ void stage_write(const StReg& s, us* Ash, int row, int lp) {
  us* d = Ash + row * AP + lp * 4;
  #pragma unroll
  for (int j = 0; j < 8; ++j) *(ull*)(d + j * 64) = s.v[j];
}
__device__ __forceinline__ void stage_xs(us* Xs, const float* X, int islbase, int t,
                                         int row, int lp) {
  const float* src = X + ((size_t)(islbase + row) * TT + t) * DD + lp * 4;
  us* d = Xs + row * AP + lp * 4;
  #pragma unroll
  for (int j = 0; j < 8; ++j) {
    float4 v = *(const float4*)(src + j * 64);
    us4 p = { f2b(v.x), f2b(v.y), f2b(v.z), f2b(v.w) };
    *(us4*)(d + j * 64) = p;
  }
}

// one 16x16 tile, K=512 half: 16 MFMA, 2 accumulators
__device__ __forceinline__ void mm_half(const us* A, const us* W, int wst, int kbase,
                                        int cc, int r16, int g4, f32x4& a0, f32x4& a1) {
  const us* ar = A + r16 * AP + g4 * 8;
  const us* br = W + cc * wst + kbase + g4 * 8;
  #pragma unroll
  for (int f = 0; f < 16; f += 2) {
    s16x8 av0 = *(const s16x8*)(ar + f * 32);
    s16x8 bv0 = *(const s16x8*)(br + f * 32);
    s16x8 av1 = *(const s16x8*)(ar + f * 32 + 32);
    s16x8 bv1 = *(const s16x8*)(br + f * 32 + 32);
    a0 = __builtin_amdgcn_mfma_f32_16x16x32_bf16(av0, bv0, a0, 0, 0, 0);
    a1 = __builtin_amdgcn_mfma_f32_16x16x32_bf16(av1, bv1, a1, 0, 0, 0);
  }
}

// in-register 4x4 transpose within a lane-quad; returns 4 cols of row (r16&3)
__device__ __forceinline__ ull quad_pack(float v0, float v1, float v2, float v3, int q) {
  unsigned p01 = (unsigned)f2b(v0) | ((unsigned)f2b(v1) << 16);
  unsigned p23 = (unsigned)f2b(v2) | ((unsigned)f2b(v3) << 16);
  unsigned o01 = __shfl_xor(p01, 2);
  unsigned o23 = __shfl_xor(p23, 2);
  unsigned x = (q < 2) ? p01 : o23;
  unsigned y = (q < 2) ? o01 : p23;
  unsigned ux = __shfl_xor(x, 1);
  unsigned uy = __shfl_xor(y, 1);
  unsigned w0, w1;
  if (q & 1) { w0 = (ux >> 16) | (x & 0xFFFF0000u); w1 = (uy >> 16) | (y & 0xFFFF0000u); }
  else       { w0 = (x & 0xFFFFu) | (ux << 16);     w1 = (y & 0xFFFFu) | (uy << 16); }
  return (ull)w0 | ((ull)w1 << 32);
}

extern "C" __global__ void __launch_bounds__(NTHR, 1)
gru_persistent(const float* __restrict__ X, const float* __restrict__ GK,
               const float* __restrict__ GB, const float* __restrict__ CK,
               const float* __restrict__ CB, float* __restrict__ Y,
               unsigned char* __restrict__ ws) {
  extern __shared__ us lds[];
  const int tid = threadIdx.x, bid = blockIdx.x;
  const int isl = (bid & 7) >> 1;                  // XCD pair {2i,2i+1}
  const int iw  = ((bid >> 3) << 1) | (bid & 1);   // 0..63 within island
  const int islbase = isl * RPI;
  const int lane = tid & 63, w = tid >> 6;
  const int r16 = lane & 15, g4 = lane >> 4;
  const int ct = w & 1;                            // col-tile (waves 2,3 duplicate)
  const int srow = tid >> 4, slp = tid & 15;       // staging map

  us* flA = (us*)(ws + (size_t)isl * 256);         // 32 flags: rh ready
  us* flB = (us*)(ws + (size_t)isl * 256 + 128);   // 32 flags: h ready
  us* hb  = (us*)(ws + WS_HB);
  us* rhb = (us*)(ws + WS_RHB);

  bool bad = false;

  if (iw < 32) {
    // ================= R-WG: 32 reset-gate cols, publish r*h =================
    us* Wg  = lds;                                 // [32][WPG]
    us* Xs  = lds + R_XS;                          // [16][AP]
    us* Ash = lds + R_ASH;                         // [16][AP]
    const int cbase = iw * 32;
    {
      const int c = tid & 31;
      for (int k = tid >> 5; k < 1536; k += 8)
        Wg[c * WPG + k] = f2b(GK[(size_t)k * 2048 + cbase + c]);
    }
    const int   cc   = ct * 16 + r16;
    const int   col  = cbase + cc;
    const float bias = GB[col];
    const int   H    = (cbase >= 512);             // which half holds own cols
    stage_xs(Xs, X, islbase, 0, srow, slp);
    __syncthreads();

    for (int t = 0; t < TT; ++t) {
      f32x4 a0 = {0.f,0.f,0.f,0.f}, a1 = {0.f,0.f,0.f,0.f};
      mm_half(Xs, Wg, WPG, 0, cc, r16, g4, a0, a1);          // x-part, pre-poll
      __syncthreads();
      if (t + 1 < TT) stage_xs(Xs, X, islbase, t + 1, srow, slp);  // overlaps poll
      if (!wait_fl(flB, (unsigned)t, lane)) { bad = true; break; }
      const us* hbR = hb + ((t + 1) & 1) * 65536 + (size_t)islbase * HH;
      StReg s0, s1;
      stage_load(s0, hbR, 0, srow, slp);
      stage_load(s1, hbR, 512, srow, slp);
      stage_write(s0, Ash, srow, slp);
      __syncthreads();
      float hv[4];
      if (!H) {
        #pragma unroll
        for (int i = 0; i < 4; ++i) hv[i] = b2f(Ash[(g4 * 4 + i) * AP + col]);
      }
      mm_half(Ash, Wg, WPG, 512, cc, r16, g4, a0, a1);
      __syncthreads();
      stage_write(s1, Ash, srow, slp);
      __syncthreads();
      mm_half(Ash, Wg, WPG, 1024, cc, r16, g4, a0, a1);
      if (H) {
        #pragma unroll
        for (int i = 0; i < 4; ++i) hv[i] = b2f(Ash[(g4 * 4 + i) * AP + (col - 512)]);
      }
      float rh[4];
      #pragma unroll
      for (int i = 0; i < 4; ++i) {                          // C/D: row=g4*4+i, col=r16
        float rv = 1.f / (1.f + __expf(-(a0[i] + a1[i] + bias)));
        rh[i] = rv * hv[i];
      }
      ull tv = quad_pack(rh[0], rh[1], rh[2], rh[3], r16 & 3);
      if (w < 2)
        cstore8(rhb + (size_t)(islbase + g4 * 4 + (r16 & 3)) * HH +
                    cbase + ct * 16 + (r16 & ~3), tv);
      __syncthreads();                                       // drain publishes
      if (tid == 0) cstore2(flA + iw, (us)(t + 1));
    }
  } else {
    // ====== C-WG: 32 cols; local u-gate (off exchange) + cand + h update ======
    us* Wu  = lds;                                 // [32][WPC]
    us* Wc  = lds + C_WC;                          // [32][WPC]
    us* Ash = lds + C_ASH;                         // [16][AP]
    const int ic = iw - 32, cbase = ic * 32;
    {
      const int c = tid & 31;
      for (int k = tid >> 5; k < 1024; k += 8) {
        Wu[c * WPC + k] = f2b(GK[(size_t)(512 + k) * 2048 + 1024 + cbase + c]);
        Wc[c * WPC + k] = f2b(CK[(size_t)(512 + k) * 1024 + cbase + c]);
      }
    }
    const int   cc    = ct * 16 + r16;
    const int   col   = cbase + cc;
    const float ubias = GB[1024 + col];
    const float cbias = CB[col];
    float hreg[4] = {0.f, 0.f, 0.f, 0.f};
    const unsigned* Yw = (const unsigned*)Y;
    __syncthreads();

    for (int t = 0; t < TT; ++t) {
      unsigned xw[4];                              // packed (xp_u<<16 | xp_c)
      #pragma unroll
      for (int i = 0; i < 4; ++i)
        xw[i] = Yw[((size_t)(islbase + g4 * 4 + i) * TT + t) * HH + col];
      if (!wait_fl(flB, (unsigned)t, lane)) { bad = true; break; }
      const us* hbR = hb + ((t + 1) & 1) * 65536 + (size_t)islbase * HH;
      us*       hbW = hb + (t & 1) * 65536;
      // ---- u-GEMM over h(t-1): overlaps R phase ----
      f32x4 u0 = {0.f,0.f,0.f,0.f}, u1 = {0.f,0.f,0.f,0.f};
      StReg s0, s1;
      stage_load(s0, hbR, 0, srow, slp);
      stage_load(s1, hbR, 512, srow, slp);
      stage_write(s0, Ash, srow, slp);
      __syncthreads();
      mm_half(Ash, Wu, WPC, 0, cc, r16, g4, u0, u1);
      __syncthreads();
      stage_write(s1, Ash, srow, slp);
      __syncthreads();
      mm_half(Ash, Wu, WPC, 512, cc, r16, g4, u0, u1);
      float uv[4];
      #pragma unroll
      for (int i = 0; i < 4; ++i)
        uv[i] = 1.f / (1.f + __expf(-(u0[i] + u1[i] +
                    b2f((us)(xw[i] >> 16)) + ubias)));
      // ---- cand GEMM over r*h(t) ----
      if (!wait_fl(flA, (unsigned)(t + 1), lane)) { bad = true; break; }
      const us* rhI = rhb + (size_t)islbase * HH;
      f32x4 c0 = {0.f,0.f,0.f,0.f}, c1 = {0.f,0.f,0.f,0.f};
      stage_load(s0, rhI, 0, srow, slp);
      stage_load(s1, rhI, 512, srow, slp);
      __syncthreads();                             // all waves done with u reads
      stage_write(s0, Ash, srow, slp);
      __syncthreads();
      mm_half(Ash, Wc, WPC, 0, cc, r16, g4, c0, c1);
      __syncthreads();
      stage_write(s1, Ash, srow, slp);
      __syncthreads();
      mm_half(Ash, Wc, WPC, 512, cc, r16, g4, c0, c1);
      float hn[4];
      #pragma unroll
      for (int i = 0; i < 4; ++i) {
        float cv = tanhf(c0[i] + c1[i] + b2f((us)(xw[i] & 0xFFFF)) + cbias);
        hn[i] = uv[i] * hreg[i] + (1.f - uv[i]) * cv;
        hreg[i] = hn[i];
        if (w < 2)
          Y[((size_t)(islbase + g4 * 4 + i) * TT + t) * HH + col] = hn[i];
      }
      ull tv = quad_pack(hn[0], hn[1], hn[2], hn[3], r16 & 3);
      if (w < 2)
        cstore8(hbW + (size_t)(islbase + g4 * 4 + (r16 & 3)) * HH +
                    cbase + ct * 16 + (r16 & ~3), tv);
      __syncthreads();                             // drain publishes
      if (tid == 0) cstore2(flB + ic, (us)(t + 1));
    }
  }
  if (bad && tid == 0) Y[1] = 31337.f;             // visible failure sentinel
}

// ---- one-time dual x-projection: Yw <- pack(bf16(X@GKu), bf16(X@CKc)) ------
// grid: 16 col-panels x 64 row-blocks; B panels LDS-resident per block.
extern "C" __global__ void __launch_bounds__(NTHR, 1)
xproj_dual(const float* __restrict__ X, const float* __restrict__ CK,
           const float* __restrict__ GK, unsigned* __restrict__ Yw) {
  extern __shared__ us lds[];
  us* Bc  = lds;                 // [64][520]
  us* Bu  = lds + 64 * 520;      // [64][520]
  us* Axs = lds + 128 * 520;     // [16][520]
  const int tid = threadIdx.x, lane = tid & 63, w = tid >> 6;
  const int r16 = lane & 15, g4 = lane >> 4;
  const int nt = blockIdx.x & 15, mb = blockIdx.x >> 4;
  const int n0 = nt * 64;
  const int srow = tid >> 4, slp = tid & 15;

  {
    const int c4 = (tid & 15) * 4;
    for (int k = tid >> 4; k < 512; k += 16) {
      float4 v  = *(const float4*)(CK + (size_t)k * HH + n0 + c4);
      // u-gate x-part rows: GK[k][1024 + n]  (v6 bug was (512+k) here)
      float4 vu = *(const float4*)(GK + (size_t)k * 2048 + 1024 + n0 + c4);
      Bc[(c4 + 0) * 520 + k] = f2b(v.x);  Bc[(c4 + 1) * 520 + k] = f2b(v.y);
      Bc[(c4 + 2) * 520 + k] = f2b(v.z);  Bc[(c4 + 3) * 520 + k] = f2b(v.w);
      Bu[(c4 + 0) * 520 + k] = f2b(vu.x); Bu[(c4 + 1) * 520 + k] = f2b(vu.y);
      Bu[(c4 + 2) * 520 + k] = f2b(vu.z); Bu[(c4 + 3) * 520 + k] = f2b(vu.w);
    }
  }
  __syncthreads();

  for (int mt = 0; mt < 32; ++mt) {
    const size_t m0 = (size_t)mb * 512 + mt * 16;
    {                                              // stage A [16][512] f32->bf16
      const float* src = X + (m0 + srow) * 512 + slp * 4;
      us* d = Axs + srow * AP + slp * 4;
      #pragma unroll
      for (int j = 0; j < 8; ++j) {
        float4 v = *(const float4*)(src + j * 64);
        us4 p = { f2b(v.x), f2b(v.y), f2b(v.z), f2b(v.w) };
        *(us4*)(d + j * 64) = p;
      }
    }
    __syncthreads();
    const int ci = w;                              // wave -> col-tile 0..3
    f32x4 ac0 = {0.f,0.f,0.f,0.f}, ac1 = {0.f,0.f,0.f,0.f};
    f32x4 au0 = {0.f,0.f,0.f,0.f}, au1 = {0.f,0.f,0.f,0.f};
    const us* ar = Axs + r16 * AP + g4 * 8;
    const us* bc = Bc + (ci * 16 + r16) * 520 + g4 * 8;
    const us* bu = Bu + (ci * 16 + r16) * 520 + g4 * 8;
    #pragma unroll
    for (int f = 0; f < 16; f += 2) {
      s16x8 a0v = *(const s16x8*)(ar + f * 32);
      s16x8 a1v = *(const s16x8*)(ar + f * 32 + 32);
      ac0 = __builtin_amdgcn_mfma_f32_16x16x32_bf16(a0v, *(const s16x8*)(bc + f * 32), ac0, 0,0,0);
      ac1 = __builtin_amdgcn_mfma_f32_16x16x32_bf16(a1v, *(const s16x8*)(bc + f * 32 + 32), ac1, 0,0,0);
      au0 = __builtin_amdgcn_mfma_f32_16x16x32_bf16(a0v, *(const s16x8*)(bu + f * 32), au0, 0,0,0);
      au1 = __builtin_amdgcn_mfma_f32_16x16x32_bf16(a1v, *(const s16x8*)(bu + f * 32 + 32), au1, 0,0,0);
    }
    #pragma unroll
    for (int i = 0; i < 4; ++i) {
      float xc = ac0[i] + ac1[i], xu = au0[i] + au1[i];
      Yw[(m0 + g4 * 4 + i) * HH + n0 + ci * 16 + r16] =
          ((unsigned)f2b(xu) << 16) | (unsigned)f2b(xc);
    }
    __syncthreads();
  }
}

extern "C" __global__ void gru_sentinel(float* out, float v) {
  if (blockIdx.x == 0 && threadIdx.x == 0) out[0] = v;
}

extern "C" void kernel_launch(void* const* d_in, const int* in_sizes, int n_in,
                              void* d_out, int out_size, void* d_ws, size_t ws_size,
                              hipStream_t stream) {
  const float* X  = (const float*)d_in[0];
  const float* GK = (const float*)d_in[1];
  const float* GB = (const float*)d_in[2];
  const float* CK = (const float*)d_in[3];
  const float* CB = (const float*)d_in[4];
  float* Y = (float*)d_out;
  unsigned char* wsb = (unsigned char*)d_ws;

  if (ws_size < (size_t)WS_NEED) {
    gru_sentinel<<<1, 64, 0, stream>>>(Y, 1000.f + (float)(ws_size >> 20));
    return;
  }

  // zero flags + both h parity buffers (h0 = 0); deterministic each call
  hipMemsetAsync(d_ws, 0, WS_HB + 2 * 64 * HH * 2, stream);

  (void)hipFuncSetAttribute((const void*)xproj_dual,
                            hipFuncAttributeMaxDynamicSharedMemorySize, XP_LDSB);
  xproj_dual<<<dim3(16 * 64), dim3(NTHR), XP_LDSB, stream>>>(X, CK, GK, (unsigned*)Y);

  (void)hipFuncSetAttribute((const void*)gru_persistent,
                            hipFuncAttributeMaxDynamicSharedMemorySize, LDS_BYTES);
  gru_persistent<<<dim3(256), dim3(NTHR), LDS_BYTES, stream>>>(X, GK, GB, CK, CB, Y, wsb);
}